// Round 6
// baseline (356.636 us; speedup 1.0000x reference)
//
#include <hip/hip_runtime.h>
#include <hip/hip_bf16.h>

// InfoNCE: a[4096,512], p[4096,512], n[16384,512] f32 -> 4 f32 scalars.
// R6: K-loop restructure. Block owns n-tile (128 rows) with B fragments fully
//     RESIDENT IN REGISTERS (64 VGPRs, loaded once); sweeps m-tiles of 64 rows,
//     staging only the 32KB A tile per iter (single buffer, 3 blocks/CU).
//     Per m-tile per wave: 32 ds_read_b128 + 128 MFMA (4:1) and ONE stage+drain,
//     hidden by the other 2 resident blocks' compute (m114 overlap).
// ws layout: a8(2MB) p8(2MB) n8(8MB) | S[4096] csA[512*16] csP[512*16] csN[512*16] lsum[1]

#define D_DIM 512
#define B_ROWS 4096
#define P_ROWS 4096
#define N_ROWS 16384
#define INV_T 14.285714285714286f
#define EPS_L 1e-8f
#define CS_STRIDE 16

typedef unsigned char fp8_t;
typedef __attribute__((ext_vector_type(4))) float floatx4;   // MFMA C/D frag
typedef __attribute__((ext_vector_type(2))) long longx2;     // 16B = 2 MFMA operands
typedef unsigned int uint32;

// ---- fused: L2-normalize rows -> fp8 e4m3, and accumulate fp32 column sums ----
__global__ __launch_bounds__(256) void norm_colsum(
        const float* __restrict__ a, const float* __restrict__ p, const float* __restrict__ n,
        fp8_t* __restrict__ a8, fp8_t* __restrict__ p8, fp8_t* __restrict__ n8,
        float* __restrict__ csA, float* __restrict__ csP, float* __restrict__ csN) {
    const float* in; fp8_t* outp; float* cs; int rows, nb, bseg;
    int b = blockIdx.x;
    if (b < 256)      { in = a; outp = a8; cs = csA; rows = B_ROWS; nb = 256; bseg = b; }
    else if (b < 512) { in = p; outp = p8; cs = csP; rows = P_ROWS; nb = 256; bseg = b - 256; }
    else              { in = n; outp = n8; cs = csN; rows = N_ROWS; nb = 512; bseg = b - 512; }

    const int wave = threadIdx.x >> 6;
    const int lane = threadIdx.x & 63;

    float cs0[4] = {0.f, 0.f, 0.f, 0.f};
    float cs1[4] = {0.f, 0.f, 0.f, 0.f};

    for (int chunk = bseg; chunk < (rows >> 2); chunk += nb) {
        int r = chunk * 4 + wave;
        const float4* rp = reinterpret_cast<const float4*>(in + (size_t)r * D_DIM);
        float4 v0 = rp[lane];
        float4 v1 = rp[lane + 64];
        float ss = v0.x*v0.x + v0.y*v0.y + v0.z*v0.z + v0.w*v0.w
                 + v1.x*v1.x + v1.y*v1.y + v1.z*v1.z + v1.w*v1.w;
#pragma unroll
        for (int off = 1; off < 64; off <<= 1) ss += __shfl_xor(ss, off);
        float inv = 1.0f / fmaxf(sqrtf(ss), 1e-12f);
        float f0x = v0.x*inv, f0y = v0.y*inv, f0z = v0.z*inv, f0w = v0.w*inv;
        float f1x = v1.x*inv, f1y = v1.y*inv, f1z = v1.z*inv, f1w = v1.w*inv;
        cs0[0] += f0x; cs0[1] += f0y; cs0[2] += f0z; cs0[3] += f0w;
        cs1[0] += f1x; cs1[1] += f1y; cs1[2] += f1z; cs1[3] += f1w;
        int pk0 = __builtin_amdgcn_cvt_pk_fp8_f32(f0x, f0y, 0, 0);
        pk0     = __builtin_amdgcn_cvt_pk_fp8_f32(f0z, f0w, pk0, 1);
        int pk1 = __builtin_amdgcn_cvt_pk_fp8_f32(f1x, f1y, 0, 0);
        pk1     = __builtin_amdgcn_cvt_pk_fp8_f32(f1z, f1w, pk1, 1);
        uint32* op = reinterpret_cast<uint32*>(outp + (size_t)r * D_DIM);
        op[lane]      = (uint32)pk0;
        op[lane + 64] = (uint32)pk1;
    }

    __shared__ float csh[D_DIM];
    if (threadIdx.x < 256) { csh[threadIdx.x] = 0.f; csh[threadIdx.x + 256] = 0.f; }
    __syncthreads();
#pragma unroll
    for (int j = 0; j < 4; ++j) {
        atomicAdd(&csh[lane * 4 + j], cs0[j]);
        atomicAdd(&csh[256 + lane * 4 + j], cs1[j]);
    }
    __syncthreads();
    if (threadIdx.x < 256) {
        atomicAdd(&cs[(size_t)threadIdx.x * CS_STRIDE], csh[threadIdx.x]);
        atomicAdd(&cs[(size_t)(threadIdx.x + 256) * CS_STRIDE], csh[threadIdx.x + 256]);
    }
}

// ---------------- fp8 MFMA GEMM: B-in-regs, A-LDS, m-swept ----------------
#define BN 128   // n-rows per block (register-resident B)
#define BMT 64   // m-rows per tile (LDS A tile = 64*512 = 32 KB)

typedef const __attribute__((address_space(1))) unsigned int* as1_u32p;
typedef __attribute__((address_space(3))) unsigned int* as3_u32p;

__device__ __forceinline__ void load_lds16(const void* g, void* l) {
    // 64 lanes x 16B at (wave-uniform l) + lane*16
    __builtin_amdgcn_global_load_lds((as1_u32p)g, (as3_u32p)l, 16, 0, 0);
}

// K-permutation (identical for A and B => dot exact): MFMA call (kb,t,h) for
// lane quad q consumes logical granule g = kb*8 + t*4 + q, half h.
// A is stored in LDS with granule slot = kb*8 + (g' ^ (r&7)) (XOR swizzle,
// conflict-free 8-lane phases since row stride 512B == 0 mod 32 banks).
// EPI==0: S[row] += sum_n exp(sim*invT)   EPI==1: loss_sum += -log(pe/(pe+S)+eps)
template <int EPI>
__global__ __launch_bounds__(256, 3) void gemm_epi(const fp8_t* __restrict__ A,
                                                   const fp8_t* __restrict__ Bm,
                                                   float* __restrict__ S,
                                                   float* __restrict__ loss_sum,
                                                   int mtiles) {
    __shared__ fp8_t As[BMT * D_DIM];  // 32 KB, single buffer

    const int tid  = threadIdx.x;
    const int lane = tid & 63;
    const int w    = tid >> 6;       // wave 0..3 -> owns n-cols [w*32, w*32+32)
    const int lr   = lane & 15;
    const int q    = lane >> 4;
    const int n0   = blockIdx.x * BN;

    // ---- B fragments resident in registers: 2ct x 4kb x 2t x 16B = 64 VGPRs ----
    longx2 Breg[2][4][2];
#pragma unroll
    for (int ct = 0; ct < 2; ++ct) {
        const fp8_t* brow = Bm + (size_t)(n0 + w * 32 + ct * 16 + lr) * D_DIM + q * 16;
#pragma unroll
        for (int kb = 0; kb < 4; ++kb)
#pragma unroll
            for (int t = 0; t < 2; ++t)
                Breg[ct][kb][t] = *reinterpret_cast<const longx2*>(brow + kb * 128 + t * 64);
    }

    // ---- staging geometry: instr i covers rows w*16+i*2+{0,1}; lane ->
    // (srow = lane>>5, slot sl = lane&31 -> kbs = sl>>3, u = sl&7); the slot
    // stores logical granule u^(r&7), so gather from col (kbs*8 + (u^(r&7)))*16.
    const int srow = lane >> 5;
    const int kbs  = (lane & 31) >> 3;
    const int u    = lane & 7;
    int stoff[8];
#pragma unroll
    for (int i = 0; i < 8; ++i) {
        int r = w * 16 + i * 2 + srow;
        stoff[i] = r * D_DIM + (kbs * 8 + (u ^ (r & 7))) * 16;
    }

    float lsum = 0.f;
    const int mbase = blockIdx.y * mtiles;

    for (int mi = 0; mi < mtiles; ++mi) {
        const int m0 = (mbase + mi) * BMT;
        if (mi) __syncthreads();               // all waves done reading prev A tile
        const fp8_t* ga = A + (size_t)m0 * D_DIM;
#pragma unroll
        for (int i = 0; i < 8; ++i)
            load_lds16(ga + stoff[i], &As[(w * 16 + i * 2) * D_DIM]);
        __syncthreads();                       // staged tile visible

        floatx4 acc[4][2];
#pragma unroll
        for (int rt = 0; rt < 4; ++rt)
#pragma unroll
            for (int ct = 0; ct < 2; ++ct) acc[rt][ct] = (floatx4){0.f, 0.f, 0.f, 0.f};

#pragma unroll
        for (int kb = 0; kb < 4; ++kb)
#pragma unroll
            for (int t = 0; t < 2; ++t) {
                longx2 a[4];
                const int scol = (kb * 8 + ((t * 4 + q) ^ (lr & 7))) * 16;
#pragma unroll
                for (int rt = 0; rt < 4; ++rt)
                    a[rt] = *reinterpret_cast<const longx2*>(&As[(rt * 16 + lr) * D_DIM + scol]);
#pragma unroll
                for (int rt = 0; rt < 4; ++rt)
#pragma unroll
                    for (int ct = 0; ct < 2; ++ct)
                        acc[rt][ct] = __builtin_amdgcn_mfma_f32_16x16x32_fp8_fp8(
                            a[rt].x, Breg[ct][kb][t].x, acc[rt][ct], 0, 0, 0);
#pragma unroll
                for (int rt = 0; rt < 4; ++rt)
#pragma unroll
                    for (int ct = 0; ct < 2; ++ct)
                        acc[rt][ct] = __builtin_amdgcn_mfma_f32_16x16x32_fp8_fp8(
                            a[rt].y, Breg[ct][kb][t].y, acc[rt][ct], 0, 0, 0);
            }

        // C/D layout: col(n) = lane&15, row(m within 16) = q*4 + reg
        if (EPI == 0) {
#pragma unroll
            for (int rt = 0; rt < 4; ++rt) {
#pragma unroll
                for (int reg = 0; reg < 4; ++reg) {
                    float v = __expf(acc[rt][0][reg] * INV_T) + __expf(acc[rt][1][reg] * INV_T);
                    v += __shfl_xor(v, 1);
                    v += __shfl_xor(v, 2);
                    v += __shfl_xor(v, 4);
                    v += __shfl_xor(v, 8);
                    if (lr == 0) atomicAdd(&S[m0 + rt * 16 + q * 4 + reg], v);
                }
            }
        } else {
#pragma unroll
            for (int rt = 0; rt < 4; ++rt) {
#pragma unroll
                for (int reg = 0; reg < 4; ++reg) {
                    float Sv = S[m0 + rt * 16 + q * 4 + reg];
#pragma unroll
                    for (int ct = 0; ct < 2; ++ct) {
                        float pe = __expf(acc[rt][ct][reg] * INV_T);
                        lsum -= __logf(pe / (pe + Sv) + EPS_L);
                    }
                }
            }
        }
    }

    if (EPI == 1) {
#pragma unroll
        for (int off = 1; off < 64; off <<= 1) lsum += __shfl_xor(lsum, off);
        if (lane == 0) atomicAdd(loss_sum, lsum);
    }
}

// ---- finalize: dot the (strided) column sums, emit the 4 scalars ----
__global__ void finalize_k(const float* __restrict__ csA, const float* __restrict__ csP,
                           const float* __restrict__ csN, const float* __restrict__ lsum,
                           float* __restrict__ out) {
    int tid = threadIdx.x;  // 512
    float av = csA[(size_t)tid * CS_STRIDE];
    float dp = av * csP[(size_t)tid * CS_STRIDE];
    float dn = av * csN[(size_t)tid * CS_STRIDE];
#pragma unroll
    for (int off = 1; off < 64; off <<= 1) {
        dp += __shfl_xor(dp, off);
        dn += __shfl_xor(dn, off);
    }
    __shared__ float red[16];
    int wid = tid >> 6, lane = tid & 63;
    if (lane == 0) { red[wid] = dp; red[8 + wid] = dn; }
    __syncthreads();
    if (tid == 0) {
        float sdp = 0.f, sdn = 0.f;
#pragma unroll
        for (int i = 0; i < 8; ++i) { sdp += red[i]; sdn += red[8 + i]; }
        float mean_pos = sdp * INV_T / ((float)B_ROWS * (float)P_ROWS);
        float mean_neg = sdn * INV_T / ((float)B_ROWS * (float)N_ROWS);
        out[0] = lsum[0] / ((float)B_ROWS * (float)P_ROWS);
        out[1] = mean_pos;
        out[2] = mean_neg;
        out[3] = mean_pos - mean_neg;
    }
}

extern "C" void kernel_launch(void* const* d_in, const int* in_sizes, int n_in,
                              void* d_out, int out_size, void* d_ws, size_t ws_size,
                              hipStream_t stream) {
    const float* anc = (const float*)d_in[0];
    const float* pos = (const float*)d_in[1];
    const float* neg = (const float*)d_in[2];
    float* out = (float*)d_out;

    fp8_t* a8 = (fp8_t*)d_ws;
    fp8_t* p8 = a8 + (size_t)B_ROWS * D_DIM;
    fp8_t* n8 = p8 + (size_t)P_ROWS * D_DIM;
    float* fsec = (float*)(n8 + (size_t)N_ROWS * D_DIM);
    float* S    = fsec;
    float* csA  = S + B_ROWS;
    float* csP  = csA + D_DIM * CS_STRIDE;
    float* csN  = csP + D_DIM * CS_STRIDE;
    float* lsum = csN + D_DIM * CS_STRIDE;

    hipMemsetAsync(fsec, 0, (B_ROWS + 3 * D_DIM * CS_STRIDE + 1) * sizeof(float), stream);

    norm_colsum<<<1024, 256, 0, stream>>>(anc, pos, neg, a8, p8, n8, csA, csP, csN);

    // neg: 128 n-tiles x 16 m-chunks (4 m-tiles of 64 rows each) = 2048 blocks
    gemm_epi<0><<<dim3(N_ROWS / BN, (B_ROWS / BMT) / 4), 256, 0, stream>>>(a8, n8, S, nullptr, 4);
    // pos: 32 n-tiles x 32 m-chunks (2 m-tiles each) = 1024 blocks
    gemm_epi<1><<<dim3(P_ROWS / BN, (B_ROWS / BMT) / 2), 256, 0, stream>>>(a8, p8, S, lsum, 2);

    finalize_k<<<1, 512, 0, stream>>>(csA, csP, csN, lsum, out);
}